// Round 2
// baseline (138.685 us; speedup 1.0000x reference)
//
#include <hip/hip_runtime.h>
#include <hip/hip_bf16.h>

#define HDIM 256
#define LDIM 384
#define BDIM 2
#define ADIM 14
#define GS 15   // G row stride (floats): gcd(15,32)=1 -> conflict-free

// ---------------------------------------------------------------------------
// Kernel 1: C(768x512) = h(768x256) @ [Wx_w; Ux_w]^T + bias
// cols 0..255   -> hw[b][i][c]       (row-major)
// cols 256..511 -> huT[b][c-256][i]  (transposed for k_main coalescing)
// 32x32 tiles, 2x2 micro-tile, transposed LDS (stride 34) + ds_read_b64.
// ---------------------------------------------------------------------------
__global__ __launch_bounds__(256) void k_gemm(
    const float* __restrict__ h,
    const float* __restrict__ Wx_w, const float* __restrict__ Wx_b,
    const float* __restrict__ Ux_w, const float* __restrict__ Ux_b,
    float* __restrict__ hw, float* __restrict__ huT)
{
    __shared__ float hsT[32][34];   // [kk][row]  stride 34: b64-aligned, 2-way max
    __shared__ float wsT[32][34];   // [kk][col]
    const int t  = threadIdx.x;          // 0..255
    const int tx = t & 15, ty = t >> 4;  // 16 x 16
    const int row0 = blockIdx.y * 32;    // 24 tiles over 768 rows
    const int col0 = blockIdx.x * 32;    // 16 tiles over 512 cols

    const int lr = t & 31;               // 0..31 (row/col within tile)
    const int lk = (t >> 5) * 4;         // 0,4,...,28
    const float* __restrict__ hrow = &h[(row0 + lr) * HDIM];
    const int c_l = col0 + lr;
    const float* __restrict__ wrow = (c_l < HDIM) ? &Wx_w[c_l * HDIM]
                                                  : &Ux_w[(c_l - HDIM) * HDIM];

    float a00 = 0.f, a01 = 0.f, a10 = 0.f, a11 = 0.f;

    for (int k0 = 0; k0 < HDIM; k0 += 32) {
        const float4 hv = *(const float4*)&hrow[k0 + lk];
        const float4 wv = *(const float4*)&wrow[k0 + lk];
        hsT[lk + 0][lr] = hv.x; hsT[lk + 1][lr] = hv.y;
        hsT[lk + 2][lr] = hv.z; hsT[lk + 3][lr] = hv.w;
        wsT[lk + 0][lr] = wv.x; wsT[lk + 1][lr] = wv.y;
        wsT[lk + 2][lr] = wv.z; wsT[lk + 3][lr] = wv.w;
        __syncthreads();
        #pragma unroll
        for (int kk = 0; kk < 32; ++kk) {
            const float2 av = *(const float2*)&hsT[kk][ty * 2];
            const float2 bv = *(const float2*)&wsT[kk][tx * 2];
            a00 = fmaf(av.x, bv.x, a00); a01 = fmaf(av.x, bv.y, a01);
            a10 = fmaf(av.y, bv.x, a10); a11 = fmaf(av.y, bv.y, a11);
        }
        __syncthreads();
    }

    const int row = row0 + ty * 2;             // even; row, row+1 same b
    const int b = row / LDIM, i0 = row % LDIM;
    const int c0 = col0 + tx * 2;
    if (c0 < HDIM) {
        const float b0 = Wx_b[c0], b1 = Wx_b[c0 + 1];
        *(float2*)&hw[row * HDIM + c0]       = make_float2(a00 + b0, a01 + b1);
        *(float2*)&hw[(row + 1) * HDIM + c0] = make_float2(a10 + b0, a11 + b1);
    } else {
        const int ch = c0 - HDIM;
        const float b0 = Ux_b[ch], b1 = Ux_b[ch + 1];
        *(float2*)&huT[(b * HDIM + ch) * LDIM + i0]     = make_float2(a00 + b0, a10 + b0);
        *(float2*)&huT[(b * HDIM + ch + 1) * LDIM + i0] = make_float2(a01 + b1, a11 + b1);
    }
}

// ---------------------------------------------------------------------------
// Kernel 2: one block per (b,i); thread j computes gate[b,i,j,:] (fp32 VALU),
// then a conflict-free segmented LDS reduction over j.
// ---------------------------------------------------------------------------
__global__ __launch_bounds__(384) void k_main(
    const float* __restrict__ hw, const float* __restrict__ huT,
    const float* __restrict__ X, const int* __restrict__ mask,
    const float* __restrict__ Tx_w, const float* __restrict__ Tx_b,
    float* __restrict__ out)
{
    __shared__ float G[LDIM * GS];    // [j][a], stride 15 (a=14 holds m)
    __shared__ float part[57][6];
    __shared__ float red[57];

    const int i = blockIdx.x;         // 0..383
    const int b = blockIdx.y;         // 0..1
    const int j = threadIdx.x;        // 0..383

    const float m = (float)mask[b * LDIM + j];
    const float* __restrict__ hwrow = &hw[(b * LDIM + i) * HDIM];   // uniform -> s_load
    const float* __restrict__ hub   = &huT[b * HDIM * LDIM + j];    // coalesced

    float g[ADIM];
    #pragma unroll
    for (int a = 0; a < ADIM; ++a) g[a] = Tx_b[a];

    #pragma unroll 8
    for (int hh = 0; hh < HDIM; ++hh) {
        const float uv = hub[hh * LDIM];
        float tv = hwrow[hh] + uv;
        tv = fmaxf(tv, 0.f);
        #pragma unroll
        for (int a = 0; a < ADIM; ++a)
            g[a] = fmaf(tv, Tx_w[a * HDIM + hh], g[a]);   // uniform -> s_load
    }

    #pragma unroll
    for (int a = 0; a < ADIM; ++a) G[j * GS + a] = g[a] * m;
    G[j * GS + ADIM] = m;
    __syncthreads();

    // phase 2: 57 sums over j (42 S2 + 14 S1 + 1 msum) x 6 segments of 64.
    // seg-major mapping: a wave spans <=2 segments -> <=2 addrs/bank -> free.
    if (j < 342) {
        const int seg = j / 57, out_id = j % 57;
        const int j0 = seg * 64;
        float p = 0.f;
        if (out_id < 42) {
            const int a = out_id / 3, c = out_id % 3;
            const float* __restrict__ Xb = &X[((b * LDIM + j0) * ADIM + a) * 3 + c];
            const float* __restrict__ Gp = &G[j0 * GS + a];
            #pragma unroll 8
            for (int jj = 0; jj < 64; ++jj)
                p = fmaf(Gp[jj * GS], Xb[jj * (ADIM * 3)], p);
        } else if (out_id < 56) {
            const int a = out_id - 42;
            const float* __restrict__ Gp = &G[j0 * GS + a];
            #pragma unroll 8
            for (int jj = 0; jj < 64; ++jj) p += Gp[jj * GS];
        } else {
            const float* __restrict__ Gp = &G[j0 * GS + ADIM];
            #pragma unroll 8
            for (int jj = 0; jj < 64; ++jj) p += Gp[jj * GS];
        }
        part[out_id][seg] = p;
    }
    __syncthreads();

    if (j < 57) {
        float s = 0.f;
        #pragma unroll
        for (int seg = 0; seg < 6; ++seg) s += part[j][seg];
        red[j] = s;
    }
    __syncthreads();

    if (j < 42) {
        const int a = j / 3, c = j % 3;
        const float denom = 1e-6f + red[56];
        const float S1 = red[42 + a];
        const float S2 = red[j];
        const int idx = ((b * LDIM + i) * ADIM + a) * 3 + c;
        const float xi = X[idx];
        float f = (xi * S1 - S2) / denom;
        f = fminf(fmaxf(f, -20.f), 20.f);
        out[idx] = xi + f;
    }
}

extern "C" void kernel_launch(void* const* d_in, const int* in_sizes, int n_in,
                              void* d_out, int out_size, void* d_ws, size_t ws_size,
                              hipStream_t stream) {
    (void)in_sizes; (void)n_in; (void)out_size; (void)ws_size;
    const float* h    = (const float*)d_in[0];
    const float* X    = (const float*)d_in[1];
    const int*   mask = (const int*)  d_in[2];
    const float* Wx_w = (const float*)d_in[3];
    const float* Wx_b = (const float*)d_in[4];
    const float* Ux_w = (const float*)d_in[5];
    const float* Ux_b = (const float*)d_in[6];
    const float* Tx_w = (const float*)d_in[7];
    const float* Tx_b = (const float*)d_in[8];
    float* out = (float*)d_out;

    float* hw  = (float*)d_ws;                 // B*L*H floats
    float* huT = hw + BDIM * LDIM * HDIM;      // B*H*L floats

    k_gemm<<<dim3(16, 24), dim3(256), 0, stream>>>(h, Wx_w, Wx_b, Ux_w, Ux_b, hw, huT);
    k_main<<<dim3(LDIM, BDIM), 384, 0, stream>>>(hw, huT, X, mask, Tx_w, Tx_b, out);
}

// Round 3
// 98.505 us; speedup vs baseline: 1.4079x; 1.4079x over previous
//
#include <hip/hip_runtime.h>
#include <hip/hip_bf16.h>

#define HDIM 256
#define LDIM 384
#define BDIM 2
#define ADIM 14

typedef __attribute__((ext_vector_type(8))) short bf16x8;
typedef __attribute__((ext_vector_type(4))) float f32x4;

static __device__ __forceinline__ unsigned pack_bf16(float x, float y) {
    __hip_bfloat162 t = __float22bfloat162_rn(make_float2(x, y));  // x -> low 16
    return *reinterpret_cast<unsigned*>(&t);
}

// ---------------------------------------------------------------------------
// Kernel 1: C(768x512) = h(768x256) @ [Wx_w; Ux_w]^T + bias
// cols 0..255   -> hw[b][i][c]              fp32 row-major
// cols 256..511 -> huP[b][(c-256)/2][i]     bf16 h-pairs packed in uint
// ---------------------------------------------------------------------------
__global__ __launch_bounds__(256) void k_gemm(
    const float* __restrict__ h,
    const float* __restrict__ Wx_w, const float* __restrict__ Wx_b,
    const float* __restrict__ Ux_w, const float* __restrict__ Ux_b,
    float* __restrict__ hw, unsigned* __restrict__ huP)
{
    __shared__ float hsT[32][34];
    __shared__ float wsT[32][34];
    const int t  = threadIdx.x;
    const int tx = t & 15, ty = t >> 4;
    const int row0 = blockIdx.y * 32;
    const int col0 = blockIdx.x * 32;

    const int lr = t & 31;
    const int lk = (t >> 5) * 4;
    const float* __restrict__ hrow = &h[(row0 + lr) * HDIM];
    const int c_l = col0 + lr;
    const float* __restrict__ wrow = (c_l < HDIM) ? &Wx_w[c_l * HDIM]
                                                  : &Ux_w[(c_l - HDIM) * HDIM];

    float a00 = 0.f, a01 = 0.f, a10 = 0.f, a11 = 0.f;

    for (int k0 = 0; k0 < HDIM; k0 += 32) {
        const float4 hv = *(const float4*)&hrow[k0 + lk];
        const float4 wv = *(const float4*)&wrow[k0 + lk];
        hsT[lk + 0][lr] = hv.x; hsT[lk + 1][lr] = hv.y;
        hsT[lk + 2][lr] = hv.z; hsT[lk + 3][lr] = hv.w;
        wsT[lk + 0][lr] = wv.x; wsT[lk + 1][lr] = wv.y;
        wsT[lk + 2][lr] = wv.z; wsT[lk + 3][lr] = wv.w;
        __syncthreads();
        #pragma unroll
        for (int kk = 0; kk < 32; ++kk) {
            const float2 av = *(const float2*)&hsT[kk][ty * 2];
            const float2 bv = *(const float2*)&wsT[kk][tx * 2];
            a00 = fmaf(av.x, bv.x, a00); a01 = fmaf(av.x, bv.y, a01);
            a10 = fmaf(av.y, bv.x, a10); a11 = fmaf(av.y, bv.y, a11);
        }
        __syncthreads();
    }

    const int row = row0 + ty * 2;            // even; row,row+1 same b
    const int b = row / LDIM, i0 = row % LDIM;
    const int c0 = col0 + tx * 2;
    if (c0 < HDIM) {
        const float b0 = Wx_b[c0], b1 = Wx_b[c0 + 1];
        *(float2*)&hw[row * HDIM + c0]       = make_float2(a00 + b0, a01 + b1);
        *(float2*)&hw[(row + 1) * HDIM + c0] = make_float2(a10 + b0, a11 + b1);
    } else {
        const int ch = c0 - HDIM;             // even
        const float b0 = Ux_b[ch], b1 = Ux_b[ch + 1];
        uint2 pv;
        pv.x = pack_bf16(a00 + b0, a01 + b1);     // residue i0:   (hu[ch], hu[ch+1])
        pv.y = pack_bf16(a10 + b0, a11 + b1);     // residue i0+1
        *(uint2*)&huP[(b * (HDIM / 2) + (ch >> 1)) * LDIM + i0] = pv;
    }
}

// ---------------------------------------------------------------------------
// Kernel 2: one block per (b,i). gate = relu(hw_i + hu_j) @ Tx_w^T via MFMA
// (M=j=384 as 24 16-tiles, N=a padded to 16, K=256 as 8 32-chunks).
// Lane builds its A-frag directly: m=lane&15 -> j, k=quad*8+idx -> h.
// D layout: col=lane&15 (=a), row=quad*4+reg (=j within tile).
// ---------------------------------------------------------------------------
__global__ __launch_bounds__(384) void k_main(
    const float* __restrict__ hw, const unsigned* __restrict__ huP,
    const float* __restrict__ X, const int* __restrict__ mask,
    const float* __restrict__ Tx_w, const float* __restrict__ Tx_b,
    float* __restrict__ out)
{
    __shared__ unsigned TxP[16 * 130];   // [n][k2] bf16-pairs, stride 130 (conflict-floor)
    __shared__ float m_lds[LDIM];
    __shared__ float part2[24 * 16 * 4]; // [g=w*4+quad][a][{s2x,s2y,s2z,s1}]
    __shared__ float part_m[24];

    const int i = blockIdx.x, b = blockIdx.y;
    const int tid = threadIdx.x;
    const int w = tid >> 6;              // wave 0..5
    const int lane = tid & 63;
    const int n = lane & 15;             // a-column / A-row-within-tile
    const int quad = lane >> 4;

    // ---- setup: Tx_w -> bf16 packed LDS; mask -> LDS
    for (int idx = tid; idx < 16 * 128; idx += 384) {
        const int nn = idx >> 7, k2 = idx & 127;
        unsigned v = 0;
        if (nn < ADIM) {
            const float2 tw = *(const float2*)&Tx_w[nn * HDIM + 2 * k2];
            v = pack_bf16(tw.x, tw.y);
        }
        TxP[nn * 130 + k2] = v;
    }
    m_lds[tid] = (float)mask[b * LDIM + tid];
    __syncthreads();

    const float* __restrict__ hwrow = &hw[(b * LDIM + i) * HDIM];
    const unsigned* __restrict__ hub = &huP[b * (HDIM / 2) * LDIM];  // [h2][j]

    f32x4 acc[4];
    #pragma unroll
    for (int t = 0; t < 4; ++t) acc[t] = (f32x4){0.f, 0.f, 0.f, 0.f};

    const int jbase = w * 64 + n;        // A-side j for tile t: jbase + t*16

    #pragma unroll 2
    for (int kc = 0; kc < 8; ++kc) {
        // B-frag (shared across the 4 tiles): Tx_w[n][kc*32+quad*8 .. +7]
        union { unsigned u[4]; bf16x8 v; } bu;
        const int bofs = n * 130 + kc * 16 + quad * 4;
        *(uint2*)&bu.u[0] = *(const uint2*)&TxP[bofs];
        *(uint2*)&bu.u[2] = *(const uint2*)&TxP[bofs + 2];
        // hw values for this lane's k-slice (L1-resident row)
        const float4 hwa = *(const float4*)(hwrow + kc * 32 + quad * 8);
        const float4 hwb = *(const float4*)(hwrow + kc * 32 + quad * 8 + 4);
        const float hv[8] = {hwa.x, hwa.y, hwa.z, hwa.w, hwb.x, hwb.y, hwb.z, hwb.w};
        const int h2base = kc * 16 + quad * 4;
        #pragma unroll
        for (int t = 0; t < 4; ++t) {
            const unsigned* __restrict__ hp = &hub[h2base * LDIM + jbase + t * 16];
            union { unsigned u[4]; bf16x8 v; } au;
            #pragma unroll
            for (int d = 0; d < 4; ++d) {
                const unsigned pk = hp[d * LDIM];
                const float lo = __uint_as_float(pk << 16);
                const float hi = __uint_as_float(pk & 0xffff0000u);
                const float t0 = fmaxf(hv[2 * d] + lo, 0.f);
                const float t1 = fmaxf(hv[2 * d + 1] + hi, 0.f);
                au.u[d] = pack_bf16(t0, t1);
            }
            acc[t] = __builtin_amdgcn_mfma_f32_16x16x32_bf16(au.v, bu.v, acc[t], 0, 0, 0);
        }
    }

    // ---- epilogue: per-lane partial sums over its 16 j's (a = n)
    float s1 = 0.f, s2x = 0.f, s2y = 0.f, s2z = 0.f, pm = 0.f;
    if (n < ADIM) {
        const float txb = Tx_b[n];
        #pragma unroll
        for (int t = 0; t < 4; ++t) {
            #pragma unroll
            for (int r = 0; r < 4; ++r) {
                const int jd = (w * 4 + t) * 16 + quad * 4 + r;
                const float m = m_lds[jd];
                const float g = acc[t][r] + txb;
                const float mg = m * g;
                const float* __restrict__ Xp = &X[((b * LDIM + jd) * ADIM + n) * 3];
                s1 += mg;
                s2x = fmaf(mg, Xp[0], s2x);
                s2y = fmaf(mg, Xp[1], s2y);
                s2z = fmaf(mg, Xp[2], s2z);
                pm += m;
            }
        }
    }
    {
        f32x4 sv = {s2x, s2y, s2z, s1};
        *(f32x4*)&part2[((w * 4 + quad) * 16 + n) * 4] = sv;
    }
    if (n == 0) part_m[w * 4 + quad] = pm;
    __syncthreads();

    if (tid < 42) {
        const int a = tid / 3, c = tid % 3;
        float S2 = 0.f, S1 = 0.f, msum = 0.f;
        #pragma unroll 4
        for (int g = 0; g < 24; ++g) {
            const float* __restrict__ p = &part2[(g * 16 + a) * 4];
            S2 += p[c]; S1 += p[3]; msum += part_m[g];
        }
        const float denom = 1e-6f + msum;
        const int idx = ((b * LDIM + i) * ADIM + a) * 3 + c;
        const float xi = X[idx];
        float f = (xi * S1 - S2) / denom;
        f = fminf(fmaxf(f, -20.f), 20.f);
        out[idx] = xi + f;
    }
}

extern "C" void kernel_launch(void* const* d_in, const int* in_sizes, int n_in,
                              void* d_out, int out_size, void* d_ws, size_t ws_size,
                              hipStream_t stream) {
    (void)in_sizes; (void)n_in; (void)out_size; (void)ws_size;
    const float* h    = (const float*)d_in[0];
    const float* X    = (const float*)d_in[1];
    const int*   mask = (const int*)  d_in[2];
    const float* Wx_w = (const float*)d_in[3];
    const float* Wx_b = (const float*)d_in[4];
    const float* Ux_w = (const float*)d_in[5];
    const float* Ux_b = (const float*)d_in[6];
    const float* Tx_w = (const float*)d_in[7];
    const float* Tx_b = (const float*)d_in[8];
    float* out = (float*)d_out;

    float*    hw  = (float*)d_ws;                        // B*L*H fp32
    unsigned* huP = (unsigned*)(hw + BDIM * LDIM * HDIM); // B*(H/2)*L packed bf16 pairs

    k_gemm<<<dim3(16, 24), dim3(256), 0, stream>>>(h, Wx_w, Wx_b, Ux_w, Ux_b, hw, huP);
    k_main<<<dim3(LDIM, BDIM), 384, 0, stream>>>(hw, huP, X, mask, Tx_w, Tx_b, out);
}